// Round 2
// baseline (226.383 us; speedup 1.0000x reference)
//
#include <hip/hip_runtime.h>

#define INV_T (1.0f / 0.07f)
#define EPSF 1e-8f

typedef __bf16 bf16x8 __attribute__((ext_vector_type(8)));
typedef float f32x4 __attribute__((ext_vector_type(4)));

__device__ __forceinline__ unsigned short f2b(float x) {
  union { float f; unsigned u; } a; a.f = x;
  return (unsigned short)((a.u + 0x7fffu + ((a.u >> 16) & 1u)) >> 16);
}

__device__ __forceinline__ void gld16(const void* g, void* l) {
  __builtin_amdgcn_global_load_lds(
      (const __attribute__((address_space(1))) unsigned int*)g,
      (__attribute__((address_space(3))) unsigned int*)l, 16, 0, 0);
}

// One wave per row: L2-normalize, cast to bf16.
__global__ __launch_bounds__(64) void norm_kernel(const float* __restrict__ emb,
                                                  unsigned short* __restrict__ ebf,
                                                  int D) {
  const int row = blockIdx.x;
  const int lane = threadIdx.x;  // 64
  const float4* src = (const float4*)(emb + (size_t)row * D);
  float4 v0 = src[lane];
  float4 v1 = src[lane + 64];
  float ss = v0.x * v0.x + v0.y * v0.y + v0.z * v0.z + v0.w * v0.w +
             v1.x * v1.x + v1.y * v1.y + v1.z * v1.z + v1.w * v1.w;
#pragma unroll
  for (int m = 32; m >= 1; m >>= 1) ss += __shfl_xor(ss, m, 64);
  const float r = 1.0f / sqrtf(ss);
  ushort4 o0, o1;
  o0.x = f2b(v0.x * r); o0.y = f2b(v0.y * r); o0.z = f2b(v0.z * r); o0.w = f2b(v0.w * r);
  o1.x = f2b(v1.x * r); o1.y = f2b(v1.y * r); o1.z = f2b(v1.z * r); o1.w = f2b(v1.w * r);
  ushort4* dst = (ushort4*)(ebf + (size_t)row * D);
  dst[lane] = o0;
  dst[lane + 64] = o1;
}

// 128x128 tile of sim = e.e^T, BK=32, 4 waves (2x2), 16x16x32 bf16 MFMA.
// Fused epilogue: exp, masks, per-row num/den partials -> atomicAdd.
__global__ __launch_bounds__(256) void sim_kernel(
    const unsigned short* __restrict__ E,   // bf16 normalized, N x D
    const int* __restrict__ labels,         // int32! harness converts int64 -> int32
    float* __restrict__ num, float* __restrict__ den,
    int D, int kTiles) {
  __shared__ unsigned short lds[2][2][128 * 32];  // [buf][A/B], 8KB each, 32KB total

  const int tid = threadIdx.x;
  const int lane = tid & 63;
  const int wave = tid >> 6;
  const int wm = wave >> 1, wn = wave & 1;  // 2x2 wave grid, 64x64 per wave
  const int i0 = blockIdx.y * 128;
  const int j0 = blockIdx.x * 128;
  const int fr = lane & 15;   // fragment row/col index
  const int fk = lane >> 4;   // k-group

  f32x4 acc[4][4] = {};

  // Stage one K-slice (128 rows x 32 bf16 = 8KB per matrix) into lds[buf].
  // LDS dest is linear (global_load_lds requirement); source column is
  // inverse-XOR-swizzled so reads can use byte ^= ((row&3)<<4)  [G21].
  auto stage = [&](int buf, int kt) {
    const int kbase = kt * 32;
#pragma unroll
    for (int c = 0; c < 2; ++c) {
      const int lo = c * 4096 + tid * 16;       // linear byte offset in 8KB tile
      const int row = lo >> 6;                  // 64B per row
      const int scb = (lo & 63) ^ ((row & 3) << 4);
      const unsigned short* gA = E + (size_t)(i0 + row) * D + kbase + (scb >> 1);
      const unsigned short* gB = E + (size_t)(j0 + row) * D + kbase + (scb >> 1);
      gld16(gA, &lds[buf][0][lo >> 1]);
      gld16(gB, &lds[buf][1][lo >> 1]);
    }
  };

  stage(0, 0);
  asm volatile("s_waitcnt vmcnt(0)" ::: "memory");
  __syncthreads();

  int cur = 0;
  for (int kt = 0; kt < kTiles; ++kt) {
    if (kt + 1 < kTiles) stage(cur ^ 1, kt + 1);

    bf16x8 a[4], b[4];
#pragma unroll
    for (int m = 0; m < 4; ++m) {
      const int row = wm * 64 + m * 16 + fr;
      const int cb = (fk * 16) ^ ((row & 3) << 4);
      a[m] = *(const bf16x8*)((const char*)&lds[cur][0][0] + row * 64 + cb);
    }
#pragma unroll
    for (int n = 0; n < 4; ++n) {
      const int row = wn * 64 + n * 16 + fr;
      const int cb = (fk * 16) ^ ((row & 3) << 4);
      b[n] = *(const bf16x8*)((const char*)&lds[cur][1][0] + row * 64 + cb);
    }
#pragma unroll
    for (int m = 0; m < 4; ++m) {
#pragma unroll
      for (int n = 0; n < 4; ++n) {
        acc[m][n] = __builtin_amdgcn_mfma_f32_16x16x32_bf16(a[m], b[n], acc[m][n], 0, 0, 0);
      }
    }
    __syncthreads();  // compiler drains vmcnt+lgkmcnt here; buffers safely swap
    cur ^= 1;
  }

  // ---- epilogue: per-element exp + masks, per-thread row partials ----
  // acc element (m,n,r): i = i0 + wm*64 + m*16 + fk*4 + r ; j = j0 + wn*64 + n*16 + fr
  float pn[16], pd[16];
#pragma unroll
  for (int t = 0; t < 16; ++t) { pn[t] = 0.f; pd[t] = 0.f; }

  int jcol[4];
  int labj[4];
#pragma unroll
  for (int n = 0; n < 4; ++n) {
    jcol[n] = j0 + wn * 64 + n * 16 + fr;
    labj[n] = labels[jcol[n]];
  }

#pragma unroll
  for (int m = 0; m < 4; ++m) {
#pragma unroll
    for (int r = 0; r < 4; ++r) {
      const int i = i0 + wm * 64 + m * 16 + fk * 4 + r;
      const int li = labels[i];
#pragma unroll
      for (int n = 0; n < 4; ++n) {
        const float s = acc[m][n][r] * INV_T;
        const float es = __expf(s);
        if (jcol[n] != i) {
          pd[m * 4 + r] += es;
          if (li == labj[n] && s > 0.0f) pn[m * 4 + r] += es;
        }
      }
    }
  }

  // reduce over the 16 lanes holding the same rows (xor over lane bits 0..3)
#pragma unroll
  for (int sh = 1; sh < 16; sh <<= 1) {
#pragma unroll
    for (int t = 0; t < 16; ++t) {
      pd[t] += __shfl_xor(pd[t], sh, 64);
      pn[t] += __shfl_xor(pn[t], sh, 64);
    }
  }

  if (fr == 0) {
#pragma unroll
    for (int m = 0; m < 4; ++m) {
#pragma unroll
      for (int r = 0; r < 4; ++r) {
        const int i = i0 + wm * 64 + m * 16 + fk * 4 + r;
        atomicAdd(&den[i], pd[m * 4 + r]);
        atomicAdd(&num[i], pn[m * 4 + r]);
      }
    }
  }
}

// Final scalar: loss_i = log(den+eps) - log(num) over valid rows; mean; abs.
__global__ __launch_bounds__(256) void loss_kernel(const float* __restrict__ num,
                                                   const float* __restrict__ den,
                                                   float* __restrict__ out, int N) {
  const int tid = threadIdx.x;
  float sum = 0.f, cnt = 0.f;
  for (int i = tid; i < N; i += 256) {
    const float n = num[i], d = den[i];
    if (n > 0.f && d > 0.f) {
      sum += logf(d + EPSF) - logf(n);
      cnt += 1.f;
    }
  }
#pragma unroll
  for (int m = 32; m >= 1; m >>= 1) {
    sum += __shfl_xor(sum, m, 64);
    cnt += __shfl_xor(cnt, m, 64);
  }
  __shared__ float s1[4], s2[4];
  if ((tid & 63) == 0) { s1[tid >> 6] = sum; s2[tid >> 6] = cnt; }
  __syncthreads();
  if (tid == 0) {
    const float S = s1[0] + s1[1] + s1[2] + s1[3];
    const float C = s2[0] + s2[1] + s2[2] + s2[3];
    out[0] = (C > 0.f) ? fabsf(S / C) : 0.f;
  }
}

extern "C" void kernel_launch(void* const* d_in, const int* in_sizes, int n_in,
                              void* d_out, int out_size, void* d_ws, size_t ws_size,
                              hipStream_t stream) {
  const float* emb = (const float*)d_in[0];
  const int* labels = (const int*)d_in[1];
  float* out = (float*)d_out;

  const int N = in_sizes[1];          // 8192
  const int D = in_sizes[0] / N;      // 512

  unsigned short* ebf = (unsigned short*)d_ws;                 // N*D bf16 = 8 MB
  float* num = (float*)((char*)d_ws + (size_t)N * D * 2);      // N f32
  float* den = num + N;                                        // N f32

  hipMemsetAsync(num, 0, 2 * (size_t)N * sizeof(float), stream);
  norm_kernel<<<N, 64, 0, stream>>>(emb, ebf, D);
  dim3 grid(N / 128, N / 128);
  sim_kernel<<<grid, 256, 0, stream>>>(ebf, labels, num, den, D, D / 32);
  loss_kernel<<<1, 256, 0, stream>>>(num, den, out, N);
}

// Round 3
// 123.707 us; speedup vs baseline: 1.8300x; 1.8300x over previous
//
#include <hip/hip_runtime.h>

#define INV_T (1.0f / 0.07f)
#define EPSF 1e-8f

typedef __bf16 bf16x8 __attribute__((ext_vector_type(8)));
typedef float f32x4 __attribute__((ext_vector_type(4)));

__device__ __forceinline__ unsigned short f2b(float x) {
  union { float f; unsigned u; } a; a.f = x;
  return (unsigned short)((a.u + 0x7fffu + ((a.u >> 16) & 1u)) >> 16);
}

__device__ __forceinline__ void gld16(const void* g, void* l) {
  __builtin_amdgcn_global_load_lds(
      (const __attribute__((address_space(1))) unsigned int*)g,
      (__attribute__((address_space(3))) unsigned int*)l, 16, 0, 0);
}

// One wave per row: L2-normalize, cast to bf16.
__global__ __launch_bounds__(64) void norm_kernel(const float* __restrict__ emb,
                                                  unsigned short* __restrict__ ebf,
                                                  int D) {
  const int row = blockIdx.x;
  const int lane = threadIdx.x;  // 64
  const float4* src = (const float4*)(emb + (size_t)row * D);
  float4 v0 = src[lane];
  float4 v1 = src[lane + 64];
  float ss = v0.x * v0.x + v0.y * v0.y + v0.z * v0.z + v0.w * v0.w +
             v1.x * v1.x + v1.y * v1.y + v1.z * v1.z + v1.w * v1.w;
#pragma unroll
  for (int m = 32; m >= 1; m >>= 1) ss += __shfl_xor(ss, m, 64);
  const float r = 1.0f / sqrtf(ss);
  ushort4 o0, o1;
  o0.x = f2b(v0.x * r); o0.y = f2b(v0.y * r); o0.z = f2b(v0.z * r); o0.w = f2b(v0.w * r);
  o1.x = f2b(v1.x * r); o1.y = f2b(v1.y * r); o1.z = f2b(v1.z * r); o1.w = f2b(v1.w * r);
  ushort4* dst = (ushort4*)(ebf + (size_t)row * D);
  dst[lane] = o0;
  dst[lane + 64] = o1;
}

// Upper-block-triangle of sim = e.e^T. 128x128 tile, BK=32, 4 waves (2x2).
// Off-diagonal blocks scatter each exp term to BOTH row i and col j (symmetry).
// LDS swizzle: byte ^= (((row>>1)&3)<<4) -> uniform 2-way (free) on ds_read_b128.
__global__ __launch_bounds__(256) void sim_kernel(
    const unsigned short* __restrict__ E,   // bf16 normalized, N x D
    const int* __restrict__ labels,         // int32 (harness converts int64)
    float* __restrict__ num, float* __restrict__ den,
    int D, int kTiles) {
  __shared__ unsigned short lds[2][2][128 * 32];  // [buf][A/B], 8KB each, 32KB total

  const int tid = threadIdx.x;
  const int lane = tid & 63;
  const int wave = tid >> 6;
  const int wm = wave >> 1, wn = wave & 1;  // 2x2 wave grid, 64x64 per wave
  const int fr = lane & 15;   // fragment row/col index
  const int fk = lane >> 4;   // k-group

  // triangular decode: t = bb*(bb+1)/2 + ba, ba <= bb
  const int t = blockIdx.x;
  int bb = (int)((sqrtf(8.0f * (float)t + 1.0f) - 1.0f) * 0.5f);
  while ((bb + 1) * (bb + 2) / 2 <= t) ++bb;
  while (bb * (bb + 1) / 2 > t) --bb;
  const int ba = t - bb * (bb + 1) / 2;
  const int i0 = ba * 128;
  const int j0 = bb * 128;
  const bool diag = (i0 == j0);

  f32x4 acc[4][4] = {};

  auto stage = [&](int buf, int kt) {
    const int kbase = kt * 32;
#pragma unroll
    for (int c = 0; c < 2; ++c) {
      const int lo = c * 4096 + tid * 16;            // linear byte offset in 8KB tile
      const int row = lo >> 6;                       // 64B per row
      const int scb = (lo & 63) ^ (((row >> 1) & 3) << 4);
      const unsigned short* gA = E + (size_t)(i0 + row) * D + kbase + (scb >> 1);
      const unsigned short* gB = E + (size_t)(j0 + row) * D + kbase + (scb >> 1);
      gld16(gA, &lds[buf][0][lo >> 1]);
      gld16(gB, &lds[buf][1][lo >> 1]);
    }
  };

  stage(0, 0);
  asm volatile("s_waitcnt vmcnt(0)" ::: "memory");
  __syncthreads();

  int cur = 0;
  for (int kt = 0; kt < kTiles; ++kt) {
    if (kt + 1 < kTiles) stage(cur ^ 1, kt + 1);

    bf16x8 a[4], b[4];
#pragma unroll
    for (int m = 0; m < 4; ++m) {
      const int row = wm * 64 + m * 16 + fr;
      const int cb = (fk * 16) ^ (((row >> 1) & 3) << 4);
      a[m] = *(const bf16x8*)((const char*)&lds[cur][0][0] + row * 64 + cb);
    }
#pragma unroll
    for (int n = 0; n < 4; ++n) {
      const int row = wn * 64 + n * 16 + fr;
      const int cb = (fk * 16) ^ (((row >> 1) & 3) << 4);
      b[n] = *(const bf16x8*)((const char*)&lds[cur][1][0] + row * 64 + cb);
    }
#pragma unroll
    for (int m = 0; m < 4; ++m) {
#pragma unroll
      for (int n = 0; n < 4; ++n) {
        acc[m][n] = __builtin_amdgcn_mfma_f32_16x16x32_bf16(a[m], b[n], acc[m][n], 0, 0, 0);
      }
    }
    __syncthreads();
    cur ^= 1;
  }

  // ---- epilogue ----
  // acc element (m,n,r): i = i0 + wm*64 + m*16 + fk*4 + r ; j = j0 + wn*64 + n*16 + fr
  float pn[16], pd[16];     // row partials, indexed m*4+r
  float cn[4], cd[4];       // col partials (off-diag only), indexed n
#pragma unroll
  for (int tt = 0; tt < 16; ++tt) { pn[tt] = 0.f; pd[tt] = 0.f; }
#pragma unroll
  for (int n = 0; n < 4; ++n) { cn[n] = 0.f; cd[n] = 0.f; }

  int jcol[4];
  int labj[4];
#pragma unroll
  for (int n = 0; n < 4; ++n) {
    jcol[n] = j0 + wn * 64 + n * 16 + fr;
    labj[n] = labels[jcol[n]];
  }

  if (diag) {
#pragma unroll
    for (int m = 0; m < 4; ++m) {
#pragma unroll
      for (int r = 0; r < 4; ++r) {
        const int i = i0 + wm * 64 + m * 16 + fk * 4 + r;
        const int li = labels[i];
#pragma unroll
        for (int n = 0; n < 4; ++n) {
          const float s = acc[m][n][r] * INV_T;
          const float es = __expf(s);
          if (jcol[n] != i) {
            pd[m * 4 + r] += es;
            if (li == labj[n] && s > 0.0f) pn[m * 4 + r] += es;
          }
        }
      }
    }
  } else {
#pragma unroll
    for (int m = 0; m < 4; ++m) {
#pragma unroll
      for (int r = 0; r < 4; ++r) {
        const int i = i0 + wm * 64 + m * 16 + fk * 4 + r;
        const int li = labels[i];
#pragma unroll
        for (int n = 0; n < 4; ++n) {
          const float s = acc[m][n][r] * INV_T;
          const float es = __expf(s);
          pd[m * 4 + r] += es;
          cd[n] += es;
          if (li == labj[n] && s > 0.0f) { pn[m * 4 + r] += es; cn[n] += es; }
        }
      }
    }
  }

  // row reduce: sum over the 16 lanes (fr) sharing the same rows
#pragma unroll
  for (int sh = 1; sh < 16; sh <<= 1) {
#pragma unroll
    for (int tt = 0; tt < 16; ++tt) {
      pd[tt] += __shfl_xor(pd[tt], sh, 64);
      pn[tt] += __shfl_xor(pn[tt], sh, 64);
    }
  }
  if (fr == 0) {
#pragma unroll
    for (int m = 0; m < 4; ++m) {
#pragma unroll
      for (int r = 0; r < 4; ++r) {
        const int i = i0 + wm * 64 + m * 16 + fk * 4 + r;
        atomicAdd(&den[i], pd[m * 4 + r]);
        atomicAdd(&num[i], pn[m * 4 + r]);
      }
    }
  }

  if (!diag) {
    // col reduce: sum over fk groups (lanes xor 16, 32); j depends on (n, fr) only
#pragma unroll
    for (int sh = 16; sh < 64; sh <<= 1) {
#pragma unroll
      for (int n = 0; n < 4; ++n) {
        cd[n] += __shfl_xor(cd[n], sh, 64);
        cn[n] += __shfl_xor(cn[n], sh, 64);
      }
    }
    if (fk == 0) {
#pragma unroll
      for (int n = 0; n < 4; ++n) {
        atomicAdd(&den[jcol[n]], cd[n]);
        atomicAdd(&num[jcol[n]], cn[n]);
      }
    }
  }
}

// Final scalar: loss_i = log(den+eps) - log(num) over valid rows; mean; abs.
__global__ __launch_bounds__(256) void loss_kernel(const float* __restrict__ num,
                                                   const float* __restrict__ den,
                                                   float* __restrict__ out, int N) {
  const int tid = threadIdx.x;
  float sum = 0.f, cnt = 0.f;
  for (int i = tid; i < N; i += 256) {
    const float n = num[i], d = den[i];
    if (n > 0.f && d > 0.f) {
      sum += logf(d + EPSF) - logf(n);
      cnt += 1.f;
    }
  }
#pragma unroll
  for (int m = 32; m >= 1; m >>= 1) {
    sum += __shfl_xor(sum, m, 64);
    cnt += __shfl_xor(cnt, m, 64);
  }
  __shared__ float s1[4], s2[4];
  if ((tid & 63) == 0) { s1[tid >> 6] = sum; s2[tid >> 6] = cnt; }
  __syncthreads();
  if (tid == 0) {
    const float S = s1[0] + s1[1] + s1[2] + s1[3];
    const float C = s2[0] + s2[1] + s2[2] + s2[3];
    out[0] = (C > 0.f) ? fabsf(S / C) : 0.f;
  }
}

extern "C" void kernel_launch(void* const* d_in, const int* in_sizes, int n_in,
                              void* d_out, int out_size, void* d_ws, size_t ws_size,
                              hipStream_t stream) {
  const float* emb = (const float*)d_in[0];
  const int* labels = (const int*)d_in[1];
  float* out = (float*)d_out;

  const int N = in_sizes[1];          // 8192
  const int D = in_sizes[0] / N;      // 512

  unsigned short* ebf = (unsigned short*)d_ws;                 // N*D bf16 = 8 MB
  float* num = (float*)((char*)d_ws + (size_t)N * D * 2);      // N f32
  float* den = num + N;                                        // N f32

  hipMemsetAsync(num, 0, 2 * (size_t)N * sizeof(float), stream);
  norm_kernel<<<N, 64, 0, stream>>>(emb, ebf, D);
  const int nb = N / 128;                       // 64
  const int tri = nb * (nb + 1) / 2;            // 2080
  sim_kernel<<<tri, 256, 0, stream>>>(ebf, labels, num, den, D, D / 32);
  loss_kernel<<<1, 256, 0, stream>>>(num, den, out, N);
}

// Round 5
// 109.329 us; speedup vs baseline: 2.0707x; 1.1315x over previous
//
#include <hip/hip_runtime.h>

#define INV_T (1.0f / 0.07f)
#define EPSF 1e-8f

typedef __bf16 bf16x8 __attribute__((ext_vector_type(8)));
typedef float f32x4 __attribute__((ext_vector_type(4)));

struct TrueT { static constexpr bool value = true; };
struct FalseT { static constexpr bool value = false; };

__device__ __forceinline__ unsigned short f2b(float x) {
  union { float f; unsigned u; } a; a.f = x;
  return (unsigned short)((a.u + 0x7fffu + ((a.u >> 16) & 1u)) >> 16);
}

__device__ __forceinline__ void gld16(const void* g, void* l) {
  __builtin_amdgcn_global_load_lds(
      (const __attribute__((address_space(1))) unsigned int*)g,
      (__attribute__((address_space(3))) unsigned int*)l, 16, 0, 0);
}

// One wave per row: L2-normalize, cast to bf16. Also zeroes num/den (replaces memset).
__global__ __launch_bounds__(64) void norm_kernel(const float* __restrict__ emb,
                                                  unsigned short* __restrict__ ebf,
                                                  float* __restrict__ num,
                                                  float* __restrict__ den,
                                                  int D) {
  const int row = blockIdx.x;
  const int lane = threadIdx.x;  // 64
  const float4* src = (const float4*)(emb + (size_t)row * D);
  float4 v0 = src[lane];
  float4 v1 = src[lane + 64];
  float ss = v0.x * v0.x + v0.y * v0.y + v0.z * v0.z + v0.w * v0.w +
             v1.x * v1.x + v1.y * v1.y + v1.z * v1.z + v1.w * v1.w;
#pragma unroll
  for (int m = 32; m >= 1; m >>= 1) ss += __shfl_xor(ss, m, 64);
  const float r = 1.0f / sqrtf(ss);
  ushort4 o0, o1;
  o0.x = f2b(v0.x * r); o0.y = f2b(v0.y * r); o0.z = f2b(v0.z * r); o0.w = f2b(v0.w * r);
  o1.x = f2b(v1.x * r); o1.y = f2b(v1.y * r); o1.z = f2b(v1.z * r); o1.w = f2b(v1.w * r);
  ushort4* dst = (ushort4*)(ebf + (size_t)row * D);
  dst[lane] = o0;
  dst[lane + 64] = o1;
  if (lane == 0) { num[row] = 0.f; den[row] = 0.f; }
}

// Upper-block-triangle of sim = e.e^T. 256x256 tile, BK=32, 8 waves (2Mx4N).
// Depth-2 prefetch pipeline: 3 LDS buffers, counted vmcnt(4) (never 0 in
// steady state), raw s_barrier. Off-diagonal blocks scatter each exp term to
// BOTH row i and col j (symmetry). LDS swizzle: byte ^= (((row>>1)&3)<<4).
__global__ __launch_bounds__(512, 2) void sim_kernel(
    const unsigned short* __restrict__ E,   // bf16 normalized, N x D
    const int* __restrict__ labels,         // int32 (harness converts int64)
    float* __restrict__ num, float* __restrict__ den,
    int D, int kTiles) {
  __shared__ unsigned short lds[3][2][256 * 32];  // [buf][A/B], 16KB each, 96KB total

  const int tid = threadIdx.x;
  const int lane = tid & 63;
  const int wave = tid >> 6;               // 0..7
  const int wm = wave >> 2, wn = wave & 3; // 2x4 wave grid: 128x64 per wave
  const int fr = lane & 15;                // fragment row/col index
  const int fk = lane >> 4;                // k-group

  // XCD-aware swizzle (528 % 8 == 0 -> simple bijective form), then
  // triangular decode: t = bb*(bb+1)/2 + ba, ba <= bb
  const int bid = blockIdx.x;
  const int t = (bid & 7) * 66 + (bid >> 3);
  int bb = (int)((sqrtf(8.0f * (float)t + 1.0f) - 1.0f) * 0.5f);
  while ((bb + 1) * (bb + 2) / 2 <= t) ++bb;
  while (bb * (bb + 1) / 2 > t) --bb;
  const int ba = t - bb * (bb + 1) / 2;
  const int i0 = ba * 256;
  const int j0 = bb * 256;
  const bool diag = (i0 == j0);

  f32x4 acc[8][4] = {};

  // per-thread constant LDS fragment byte offsets (swizzle XOR is fr-only)
  const int swz = ((fr >> 1) & 3) << 4;
  const int cbk = (fk * 16) ^ swz;
  int aoff[8], boff[4];
#pragma unroll
  for (int m = 0; m < 8; ++m) aoff[m] = (wm * 128 + m * 16 + fr) * 64 + cbk;
#pragma unroll
  for (int n = 0; n < 4; ++n) boff[n] = (wn * 64 + n * 16 + fr) * 64 + cbk;

  // stage one K-tile (256 rows x 32 cols per matrix, 16KB each) into buf.
  // LDS dest linear (wave-uniform base + lane*16); source col inverse-swizzled.
  auto stage = [&](int buf, int kt) {
    const int kbase = kt * 32;
#pragma unroll
    for (int c = 0; c < 2; ++c) {
      const int lo = c * 8192 + tid * 16;            // byte offset in 16KB tile
      const int row = lo >> 6;                       // 64B per row
      const int scb = (lo & 63) ^ (((row >> 1) & 3) << 4);
      const unsigned short* gA = E + (size_t)(i0 + row) * D + kbase + (scb >> 1);
      const unsigned short* gB = E + (size_t)(j0 + row) * D + kbase + (scb >> 1);
      gld16(gA, &lds[buf][0][lo >> 1]);
      gld16(gB, &lds[buf][1][lo >> 1]);
    }
  };

  auto compute = [&](int cb) {
    const char* Ab = (const char*)&lds[cb][0][0];
    const char* Bb = (const char*)&lds[cb][1][0];
    bf16x8 a[8], b[4];
#pragma unroll
    for (int m = 0; m < 8; ++m) a[m] = *(const bf16x8*)(Ab + aoff[m]);
#pragma unroll
    for (int n = 0; n < 4; ++n) b[n] = *(const bf16x8*)(Bb + boff[n]);
    __builtin_amdgcn_s_setprio(1);
#pragma unroll
    for (int m = 0; m < 8; ++m)
#pragma unroll
      for (int n = 0; n < 4; ++n)
        acc[m][n] = __builtin_amdgcn_mfma_f32_16x16x32_bf16(a[m], b[n], acc[m][n], 0, 0, 0);
    __builtin_amdgcn_s_setprio(0);
  };

  // prologue: stage tiles 0 and 1; wait for tile 0 (own 4 oldest loads) + barrier
  stage(0, 0);
  stage(1, 1);
  asm volatile("s_waitcnt vmcnt(4)" ::: "memory");
  __builtin_amdgcn_s_barrier();

  int cur = 0, sb = 2;
  // steady: compute kt from buf[cur]; stage kt+2 into buf[sb]; vmcnt(4) -> kt+1 landed
  for (int kt = 0; kt < kTiles - 2; ++kt) {
    stage(sb, kt + 2);
    compute(cur);
    asm volatile("s_waitcnt vmcnt(4)" ::: "memory");  // tile kt+1 complete; kt+2 in flight
    __builtin_amdgcn_s_barrier();                     // all reads of buf[cur] done
    cur = (cur == 2) ? 0 : cur + 1;
    sb = (sb == 2) ? 0 : sb + 1;
  }
  // kt = kTiles-2: nothing left to stage; drain so last tile is complete
  compute(cur);
  asm volatile("s_waitcnt vmcnt(0)" ::: "memory");
  __builtin_amdgcn_s_barrier();
  cur = (cur == 2) ? 0 : cur + 1;
  // kt = kTiles-1: last compute, no sync needed after
  compute(cur);

  // ---- epilogue ----
  // acc[m][n][r]: i = i0 + wm*128 + m*16 + fk*4 + r ; j = j0 + wn*64 + n*16 + fr
  int jcol[4], labj[4];
#pragma unroll
  for (int n = 0; n < 4; ++n) {
    jcol[n] = j0 + wn * 64 + n * 16 + fr;
    labj[n] = labels[jcol[n]];
  }
  float cd[4] = {0.f, 0.f, 0.f, 0.f}, cn[4] = {0.f, 0.f, 0.f, 0.f};

  auto epilogue = [&](auto DIAG) {
#pragma unroll
    for (int m = 0; m < 8; ++m) {
      float pdm[4] = {0.f, 0.f, 0.f, 0.f}, pnm[4] = {0.f, 0.f, 0.f, 0.f};
      const int ibase = i0 + wm * 128 + m * 16 + fk * 4;
      int li[4];
#pragma unroll
      for (int r = 0; r < 4; ++r) li[r] = labels[ibase + r];
#pragma unroll
      for (int n = 0; n < 4; ++n) {
#pragma unroll
        for (int r = 0; r < 4; ++r) {
          const float s = acc[m][n][r] * INV_T;
          const float es = __expf(s);
          if (DIAG.value) {
            if (jcol[n] != ibase + r) {
              pdm[r] += es;
              if (li[r] == labj[n] && s > 0.0f) pnm[r] += es;
            }
          } else {
            pdm[r] += es;
            cd[n] += es;
            if (li[r] == labj[n] && s > 0.0f) { pnm[r] += es; cn[n] += es; }
          }
        }
      }
      // reduce over the 16 fr-lanes sharing these rows
#pragma unroll
      for (int sh = 1; sh < 16; sh <<= 1) {
#pragma unroll
        for (int r = 0; r < 4; ++r) {
          pdm[r] += __shfl_xor(pdm[r], sh, 64);
          pnm[r] += __shfl_xor(pnm[r], sh, 64);
        }
      }
      if (fr == 0) {
#pragma unroll
        for (int r = 0; r < 4; ++r) {
          atomicAdd(&den[ibase + r], pdm[r]);
          atomicAdd(&num[ibase + r], pnm[r]);
        }
      }
    }
  };

  if (diag) epilogue(TrueT{}); else epilogue(FalseT{});

  if (!diag) {
    // col partials: j depends on (n, fr) only; reduce over fk (lanes xor 16,32)
#pragma unroll
    for (int sh = 16; sh < 64; sh <<= 1) {
#pragma unroll
      for (int n = 0; n < 4; ++n) {
        cd[n] += __shfl_xor(cd[n], sh, 64);
        cn[n] += __shfl_xor(cn[n], sh, 64);
      }
    }
    if (fk == 0) {
#pragma unroll
      for (int n = 0; n < 4; ++n) {
        atomicAdd(&den[jcol[n]], cd[n]);
        atomicAdd(&num[jcol[n]], cn[n]);
      }
    }
  }
}

// Final scalar: loss_i = log(den+eps) - log(num) over valid rows; mean; abs.
__global__ __launch_bounds__(256) void loss_kernel(const float* __restrict__ num,
                                                   const float* __restrict__ den,
                                                   float* __restrict__ out, int N) {
  const int tid = threadIdx.x;
  float sum = 0.f, cnt = 0.f;
  for (int i = tid; i < N; i += 256) {
    const float n = num[i], d = den[i];
    if (n > 0.f && d > 0.f) {
      sum += logf(d + EPSF) - logf(n);
      cnt += 1.f;
    }
  }
#pragma unroll
  for (int m = 32; m >= 1; m >>= 1) {
    sum += __shfl_xor(sum, m, 64);
    cnt += __shfl_xor(cnt, m, 64);
  }
  __shared__ float s1[4], s2[4];
  if ((tid & 63) == 0) { s1[tid >> 6] = sum; s2[tid >> 6] = cnt; }
  __syncthreads();
  if (tid == 0) {
    const float S = s1[0] + s1[1] + s1[2] + s1[3];
    const float C = s2[0] + s2[1] + s2[2] + s2[3];
    out[0] = (C > 0.f) ? fabsf(S / C) : 0.f;
  }
}

extern "C" void kernel_launch(void* const* d_in, const int* in_sizes, int n_in,
                              void* d_out, int out_size, void* d_ws, size_t ws_size,
                              hipStream_t stream) {
  const float* emb = (const float*)d_in[0];
  const int* labels = (const int*)d_in[1];
  float* out = (float*)d_out;

  const int N = in_sizes[1];          // 8192
  const int D = in_sizes[0] / N;      // 512

  unsigned short* ebf = (unsigned short*)d_ws;                 // N*D bf16 = 8 MB
  float* num = (float*)((char*)d_ws + (size_t)N * D * 2);      // N f32
  float* den = num + N;                                        // N f32

  norm_kernel<<<N, 64, 0, stream>>>(emb, ebf, num, den, D);
  const int nb = N / 256;                       // 32
  const int tri = nb * (nb + 1) / 2;            // 528
  sim_kernel<<<tri, 512, 0, stream>>>(ebf, labels, num, den, D, D / 32);
  loss_kernel<<<1, 256, 0, stream>>>(num, den, out, N);
}